// Round 7
// baseline (313.377 us; speedup 1.0000x reference)
//
#include <hip/hip_runtime.h>

#define D 4096
#define RANK 8

typedef float f4 __attribute__((ext_vector_type(4)));

// ===========================================================================
// Round 7: per-wave fused dots+apply (no C round-trip, no second launch).
//   H = I - Vn T Vn^T  (compact WY, Vn = column-normalized hra_u)
//   c[k]    = sum_d x[d] * VnT[k][d]          (pass 1, per wave, 2 rows)
//   y[d]    = x[d] - sum_k c[k] * B[k][d]     (pass 2, same wave, same rows)
//   B[k][d] = sum_j Vn[d][j] * T[j][k]
// K0: setup (1 block) -> VnT[8][D], B[8][D] in workspace (coalesced k-major).
// K1: fused; one wave per row-pair; wave-local butterfly only; ZERO block
//     barriers. Pass-2 x re-reads (32 KB/wave, just streamed) come from
//     L1/L2/L3; basis (256 KB) is L2-resident per XCD. Nontemporal y stores
//     keep X resident in L3 for other waves' pass 2.
// History: r5 d-major Vn loads were uncoalesced (100us @ 670 GB/s); r6 fixed
// coalescing (K1 ~45-55us). r0-r4: monolithic barrier'd block capped at
// ~2 TB/s duty cycle; occupancy is the BW lever (r3: 3.87 TB/s @ 79% occ).
// ===========================================================================

__global__ __launch_bounds__(1024) void hra_setup(
    const float* __restrict__ u_raw, float* __restrict__ vnT_out,
    float* __restrict__ B_out) {
  __shared__ float s_g[16][36];
  __shared__ float s_G[36];
  __shared__ float s_Gn[64];
  __shared__ float s_T[64];
  __shared__ float s_invn[8];

  const int t = threadIdx.x;
  const int lane = t & 63;
  const int wid = t >> 6;

  float v[4][8];
#pragma unroll
  for (int q = 0; q < 4; ++q) {
    const int d = 4 * t + q;
    const f4* p = (const f4*)(u_raw + (size_t)d * RANK);
    f4 a0 = p[0];
    f4 a1 = p[1];
    v[q][0] = a0.x; v[q][1] = a0.y; v[q][2] = a0.z; v[q][3] = a0.w;
    v[q][4] = a1.x; v[q][5] = a1.y; v[q][6] = a1.z; v[q][7] = a1.w;
  }

  {  // Gram partials (packed upper triangle)
    float g[36];
#pragma unroll
    for (int k = 0; k < 36; ++k) g[k] = 0.f;
#pragma unroll
    for (int q = 0; q < 4; ++q) {
      int idx = 0;
#pragma unroll
      for (int i = 0; i < 8; ++i)
#pragma unroll
        for (int j = i; j < 8; ++j)
          g[idx++] += v[q][i] * v[q][j];
    }
#pragma unroll
    for (int off = 32; off >= 1; off >>= 1) {
#pragma unroll
      for (int k = 0; k < 36; ++k)
        g[k] += __shfl_xor(g[k], off, 64);
    }
    if (lane == 0) {
#pragma unroll
      for (int k = 0; k < 36; ++k) s_g[wid][k] = g[k];
    }
  }
  __syncthreads();

  if (t < 36) {
    float s = 0.f;
#pragma unroll
    for (int w2 = 0; w2 < 16; ++w2) s += s_g[w2][t];
    s_G[t] = s;
  }
  __syncthreads();

  if (t < 8) {
    const int dix[8] = {0, 8, 15, 21, 26, 30, 33, 35};
    s_invn[t] = rsqrtf(s_G[dix[t]]);
  }
  __syncthreads();

  if (t < 64) {
    const int i = t >> 3, j = t & 7;
    const int ii = i < j ? i : j;
    const int jj = i < j ? j : i;
    const int idx = ii * 8 - (ii * (ii - 1)) / 2 + (jj - ii);
    s_Gn[t] = s_G[idx] * s_invn[i] * s_invn[j];
  }
  __syncthreads();

  if (t < 8) {  // column-parallel WY recurrence
    const int j = t;
    for (int k = 0; k < j; ++k) s_T[k * 8 + j] = 0.f;
    s_T[j * 8 + j] = 2.f;
    for (int k = j + 1; k < 8; ++k) {
      float s = 0.f;
      for (int l = j; l < k; ++l) s += s_Gn[k * 8 + l] * s_T[l * 8 + j];
      s_T[k * 8 + j] = -2.f * s;
    }
  }
  __syncthreads();

  // normalize V
  {
    float invn[8];
#pragma unroll
    for (int i = 0; i < 8; ++i) invn[i] = s_invn[i];
#pragma unroll
    for (int q = 0; q < 4; ++q)
#pragma unroll
      for (int i = 0; i < 8; ++i) v[q][i] *= invn[i];
  }

  // VnT[k][d] (k-major): thread owns d = 4t..4t+3 -> coalesced f4 stores
#pragma unroll
  for (int k = 0; k < 8; ++k) {
    f4 b = {v[0][k], v[1][k], v[2][k], v[3][k]};
    *(f4*)(vnT_out + (size_t)k * D + 4 * t) = b;
  }

  // B[k][d] = sum_j Vn[d][j] * T[j][k]
#pragma unroll
  for (int k = 0; k < 8; ++k) {
    float Tk[8];
#pragma unroll
    for (int j = 0; j < 8; ++j) Tk[j] = s_T[j * 8 + k];  // uniform -> broadcast
    float bq[4];
#pragma unroll
    for (int q = 0; q < 4; ++q) {
      float s = 0.f;
#pragma unroll
      for (int j = 0; j < 8; ++j) s += v[q][j] * Tk[j];
      bq[q] = s;
    }
    f4 b = {bq[0], bq[1], bq[2], bq[3]};
    *(f4*)(B_out + (size_t)k * D + 4 * t) = b;
  }
}

// ---------------------------------------------------------------------------
// Fused dots+apply. One wave per row-pair; no barriers anywhere.
// ---------------------------------------------------------------------------
#define FK_BLOCK 256
__global__ __launch_bounds__(FK_BLOCK) void hra_fused2(
    const float* __restrict__ x_in, const float* __restrict__ vnT,
    const float* __restrict__ B, float* __restrict__ y, int rows) {
  const int lane = threadIdx.x & 63;
  const int wv = blockIdx.x * (FK_BLOCK / 64) + (threadIdx.x >> 6);
  const int r0 = wv * 2;
  if (r0 >= rows) return;

  const float* x0 = x_in + (size_t)r0 * D;
  const float* x1 = x0 + D;

  // ---- pass 1: c = VnT * x for both rows (coalesced; basis L2-hot) ----
  float acc0[8], acc1[8];
#pragma unroll
  for (int i = 0; i < 8; ++i) { acc0[i] = 0.f; acc1[i] = 0.f; }

#pragma unroll 2
  for (int it = 0; it < 16; ++it) {
    const int d = it * 256 + lane * 4;
    f4 a = *(const f4*)(x0 + d);
    f4 b = *(const f4*)(x1 + d);
    f4 vk[8];
#pragma unroll
    for (int k = 0; k < 8; ++k)
      vk[k] = *(const f4*)(vnT + (size_t)k * D + d);
#pragma unroll
    for (int k = 0; k < 8; ++k) {
      acc0[k] += a.x * vk[k].x + a.y * vk[k].y + a.z * vk[k].z + a.w * vk[k].w;
      acc1[k] += b.x * vk[k].x + b.y * vk[k].y + b.z * vk[k].z + b.w * vk[k].w;
    }
  }

  // ---- wave butterfly: full c in every lane ----
#pragma unroll
  for (int off = 32; off >= 1; off >>= 1) {
#pragma unroll
    for (int i = 0; i < 8; ++i) {
      acc0[i] += __shfl_xor(acc0[i], off, 64);
      acc1[i] += __shfl_xor(acc1[i], off, 64);
    }
  }

  // ---- pass 2: y = x - sum_k c_k B_k (x re-read from L1/L2/L3) ----
  float* y0 = y + (size_t)r0 * D;
  float* y1 = y0 + D;

#pragma unroll 2
  for (int it = 0; it < 16; ++it) {
    const int d = it * 256 + lane * 4;
    f4 a = *(const f4*)(x0 + d);
    f4 b = *(const f4*)(x1 + d);
    f4 s0 = {0.f, 0.f, 0.f, 0.f};
    f4 s1 = {0.f, 0.f, 0.f, 0.f};
#pragma unroll
    for (int k = 0; k < 8; ++k) {
      f4 Bk = *(const f4*)(B + (size_t)k * D + d);
      s0 += acc0[k] * Bk;
      s1 += acc1[k] * Bk;
    }
    f4 o0 = a - s0;
    f4 o1 = b - s1;
    __builtin_nontemporal_store(o0, (f4*)(y0 + d));
    __builtin_nontemporal_store(o1, (f4*)(y1 + d));
  }
}

extern "C" void kernel_launch(void* const* d_in, const int* in_sizes, int n_in,
                              void* d_out, int out_size, void* d_ws, size_t ws_size,
                              hipStream_t stream) {
  const float* x_in = (const float*)d_in[0];
  const float* u = (const float*)d_in[1];
  float* y = (float*)d_out;
  (void)n_in; (void)out_size; (void)ws_size;

  const int rows = in_sizes[0] / D;  // 8192

  float* vnT = (float*)d_ws;           // 8*D floats = 128 KB
  float* B = vnT + (size_t)RANK * D;   // 8*D floats = 128 KB

  hipLaunchKernelGGL(hra_setup, dim3(1), dim3(1024), 0, stream, u, vnT, B);

  // one wave per row-pair: rows/2 waves, 4 waves/block
  const int grid = (rows / 2) / (FK_BLOCK / 64);  // 1024
  hipLaunchKernelGGL(hra_fused2, dim3(grid), dim3(FK_BLOCK), 0, stream,
                     x_in, vnT, B, y, rows);
}